// Round 13
// baseline (240.339 us; speedup 1.0000x reference)
//
#include <hip/hip_runtime.h>
#include <hip/hip_bf16.h>
#include <math.h>

#define N_NODES 100000
#define DIM 128
#define HID 512
#define EDGES 600000
#define SCAN_CHUNK 1024
#define SCAN_NBLK ((N_NODES + SCAN_CHUNK - 1) / SCAN_CHUNK)  // 98
#define MROWS_PAD 100096   // 782 * 128

typedef short bf16x8 __attribute__((ext_vector_type(8)));
typedef float f32x4 __attribute__((ext_vector_type(4)));

// Swizzle convention (rule #21 both-sides): for every bf16 staging buffer
// (X, W1T, W2T) physical byte within a row = logical byte XOR ((row&7)<<4).
// XOR touches bits 4..6 only -> permutes 16-B slots within each 128-B block,
// so any 128-B-aligned sub-chunk copied linearly (global_load_lds) keeps the
// same internal permutation; reads apply the same XOR.

__device__ inline unsigned short f32_to_bf16(float f) {
    unsigned int u = __float_as_uint(f);
    u += 0x7fff + ((u >> 16) & 1);
    return (unsigned short)(u >> 16);
}

// fast GELU: tanh form via hw exp2 + rcp. |gelu_tanh - gelu_erf| <= ~5e-4.
__device__ inline float gelu_f(float x) {
    float x3 = x * x * x;
    float y = 0.7978845608028654f * x + 0.0356774081f * x3;
    float e = exp2f(y * 2.8853900817779268f);                 // exp(2y)
    float t = 1.0f - 2.0f * __builtin_amdgcn_rcpf(e + 1.0f);  // tanh(y)
    return 0.5f * x * (1.0f + t);
}

__device__ inline void gload16(const void* g, void* l) {
    __builtin_amdgcn_global_load_lds(
        (const __attribute__((address_space(1))) unsigned int*)g,
        (__attribute__((address_space(3))) unsigned int*)l,
        16, 0, 0);
}

// ---------------------------------------------------------------------------
// Fused prep kernel: W1 transpose | W2 transpose | h->bf16 convert | dst count
// ---------------------------------------------------------------------------
#define PREP_W1_BLKS 512
#define PREP_W2_BLKS 128
#define PREP_CONV_BLKS 12500                  // N_NODES*32/256
#define PREP_COUNT_BLKS ((EDGES + 255) / 256) // 2344
#define PREP_TOTAL (PREP_W1_BLKS + PREP_W2_BLKS + PREP_CONV_BLKS + PREP_COUNT_BLKS)

__global__ __launch_bounds__(256) void mgl_prep_kernel(
    const float* __restrict__ h, const int* __restrict__ ei,
    const float* __restrict__ W1, const float* __restrict__ W2,
    unsigned short* __restrict__ X, unsigned short* __restrict__ W1T,
    unsigned short* __restrict__ W2T, int* __restrict__ cnt)
{
    int b = blockIdx.x;
    if (b < PREP_W1_BLKS) {
        int n = b;                       // 0..511
        int k = threadIdx.x;             // 0..255
        unsigned short val = f32_to_bf16(W1[(size_t)k * HID + n]);
        int byteoff = (k * 2) ^ ((n & 7) << 4);
        *(unsigned short*)((char*)(W1T + (size_t)n * 256) + byteoff) = val;
        return;
    }
    b -= PREP_W1_BLKS;
    if (b < PREP_W2_BLKS) {
        int n = b;                       // 0..127
        #pragma unroll
        for (int it = 0; it < 2; ++it) {
            int k = threadIdx.x + it * 256;  // 0..511
            unsigned short val = f32_to_bf16(W2[(size_t)k * DIM + n]);
            int byteoff = (k * 2) ^ ((n & 7) << 4);
            *(unsigned short*)((char*)(W2T + (size_t)n * 512) + byteoff) = val;
        }
        return;
    }
    b -= PREP_W2_BLKS;
    if (b < PREP_CONV_BLKS) {
        int t = b * 256 + threadIdx.x;
        if (t >= N_NODES * (DIM / 4)) return;
        int node = t >> 5;               // 32 float4 per node
        int c4 = t & 31;
        float4 v = *(const float4*)(h + (size_t)node * DIM + c4 * 4);
        ushort4 p;
        p.x = f32_to_bf16(v.x); p.y = f32_to_bf16(v.y);
        p.z = f32_to_bf16(v.z); p.w = f32_to_bf16(v.w);
        int byteoff = (c4 * 8) ^ ((node & 7) << 4);
        *(ushort4*)((char*)(X + (size_t)node * 256) + byteoff) = p;
        return;
    }
    b -= PREP_CONV_BLKS;
    {
        int e = b * 256 + threadIdx.x;
        if (e < EDGES) atomicAdd(&cnt[ei[EDGES + e]], 1);
    }
}

// ---------------------------------------------------------------------------
// Scan (3 kernels)
// ---------------------------------------------------------------------------
__global__ __launch_bounds__(256) void mgl_scan_block_kernel(
    const int* __restrict__ cnt, int* __restrict__ row_start, int* __restrict__ bsum)
{
    __shared__ int sdata[256];
    int t = threadIdx.x;
    int base = blockIdx.x * SCAN_CHUNK + t * 4;
    int v[4];
    #pragma unroll
    for (int i = 0; i < 4; ++i) {
        int idx = base + i;
        v[i] = (idx < N_NODES) ? cnt[idx] : 0;
    }
    int tsum = v[0] + v[1] + v[2] + v[3];
    sdata[t] = tsum;
    __syncthreads();
    for (int off = 1; off < 256; off <<= 1) {
        int x = (t >= off) ? sdata[t - off] : 0;
        __syncthreads();
        sdata[t] += x;
        __syncthreads();
    }
    int run = (t > 0) ? sdata[t - 1] : 0;
    #pragma unroll
    for (int i = 0; i < 4; ++i) {
        int idx = base + i;
        if (idx < N_NODES) row_start[idx] = run;
        run += v[i];
    }
    if (t == 255) bsum[blockIdx.x] = sdata[255];
}

__global__ __launch_bounds__(128) void mgl_scan_bsum_kernel(int* __restrict__ bsum)
{
    __shared__ int sd[128];
    int t = threadIdx.x;
    int v = (t < SCAN_NBLK) ? bsum[t] : 0;
    sd[t] = v;
    __syncthreads();
    for (int off = 1; off < 128; off <<= 1) {
        int x = (t >= off) ? sd[t - off] : 0;
        __syncthreads();
        sd[t] += x;
        __syncthreads();
    }
    if (t < SCAN_NBLK) bsum[t] = sd[t] - v;  // exclusive
}

__global__ __launch_bounds__(256) void mgl_scan_add_kernel(
    int* __restrict__ row_start, const int* __restrict__ bsum)
{
    int i = blockIdx.x * 256 + threadIdx.x;
    if (i < N_NODES) row_start[i] += bsum[i / SCAN_CHUNK];
    if (i == 0) row_start[N_NODES] = EDGES;
}

// ---------------------------------------------------------------------------
// Fill: consume leftover counts with atomicSub (cnt ends 0 -> deterministic).
// ---------------------------------------------------------------------------
__global__ __launch_bounds__(256) void mgl_fill_kernel(
    const int* __restrict__ ei, const int* __restrict__ row_start,
    int* __restrict__ cnt, int* __restrict__ csr)
{
    int e = blockIdx.x * 256 + threadIdx.x;
    if (e >= EDGES) return;
    int s = ei[e];
    int t = ei[EDGES + e];
    int pos = atomicSub(&cnt[t], 1) - 1;
    csr[row_start[t] + pos] = s;
}

// ---------------------------------------------------------------------------
// Gather-mean (one wave/node): neighbor ids loaded 64-wide, shfl-broadcast.
// ---------------------------------------------------------------------------
__global__ __launch_bounds__(256) void mgl_gather_mean_kernel(
    const unsigned short* __restrict__ Xb, const int* __restrict__ row_start,
    const int* __restrict__ csr, unsigned short* __restrict__ X)
{
    int v = blockIdx.x * 4 + (threadIdx.x >> 6);
    if (v >= N_NODES) return;
    int lane = threadIdx.x & 63;
    int beg = row_start[v];
    int nb = row_start[v + 1] - beg;
    int laneByte = lane * 4;
    const char* xb = (const char*)Xb;

    if (nb > 0) {
        float2 acc = make_float2(0.f, 0.f);
        for (int base = 0; base < nb; base += 64) {
            int rem = nb - base; if (rem > 64) rem = 64;
            int sv = (lane < rem) ? csr[beg + base + lane] : 0;
            for (int j = 0; j < rem; ++j) {
                int s = __shfl(sv, j);
                unsigned int pk = *(const unsigned int*)(
                    xb + (size_t)s * 512 + (laneByte ^ ((s & 7) << 4)));
                acc.x += __uint_as_float(pk << 16);
                acc.y += __uint_as_float(pk & 0xffff0000u);
            }
        }
        float inv = 1.f / (float)nb;
        unsigned int po = (unsigned int)f32_to_bf16(acc.x * inv) |
                          ((unsigned int)f32_to_bf16(acc.y * inv) << 16);
        *(unsigned int*)((char*)(X + (size_t)v * 256) +
                         ((256 + laneByte) ^ ((v & 7) << 4))) = po;
    } else {
        unsigned int pk = *(const unsigned int*)(
            xb + (size_t)v * 512 + (laneByte ^ ((v & 7) << 4)));
        *(unsigned int*)((char*)(X + (size_t)v * 256) +
                         ((256 + laneByte) ^ ((v & 7) << 4))) = pk;
    }
}

// ---------------------------------------------------------------------------
// FUSED MLP v2: out = gelu(X @ W1^T + b1) @ W2^T + b2, 2-m-frag waves.
// Block = 128 rows, 4 waves x 32 rows (2 m-frags each). Per h-tile t:
//   stage W1-tile [64h][256k] (32 KB) + W2-slice [128o][64h] (16 KB) -> sync
//   phase1: each W1-frag ds_read feeds TWO mfma (s0,s1); bias+gelu -> bf16
//           -> wave-private LDS bounce (32 rows x 128 B)
//   phase2: each W2-frag ds_read feeds TWO mfma; bounce read feeds 8.
//   -> sync.
// LDS reads/tile/wave = 52 for 96 MFMA (0.54/MFMA, half of v1) -> total LDS
// read traffic 1.33 GB (~19 us floor at 69 TB/s). hdn never hits HBM.
// LDS 64 KB -> 2 blocks/CU; acc in unified AGPR file.
// ---------------------------------------------------------------------------
__global__ __launch_bounds__(256, 2) void mgl_fused_mlp_kernel(
    const unsigned short* __restrict__ W1T,  // [512][256] bf16 swizzled
    const unsigned short* __restrict__ W2T,  // [128][512] bf16 swizzled
    const unsigned short* __restrict__ Xr,   // [MROWS_PAD][256] bf16 swizzled
    const float* __restrict__ b1f, const float* __restrict__ b2f,
    float* __restrict__ outp)
{
    __shared__ char lds[65536];
    char* W1l = lds;                       // 32 KB  [64 h-rows][512 B]
    char* W2l = lds + 32768;               // 16 KB  [128 o-rows][128 B]
    const int tid = threadIdx.x;           // 0..255
    const int w = tid >> 6, l = tid & 63;  // w 0..3
    const int r16 = l & 15, kq = l >> 4;
    const int rmask = (r16 & 7) << 4;
    char* bnc = lds + 49152 + w * 4096;    // wave-private 32 rows x 128 B

    const size_t m0 = (size_t)blockIdx.x * 128;

    // ---- X fragments -> registers (64 VGPR), loaded once: 2 m-frags ----
    bf16x8 xf[2][8];
    #pragma unroll
    for (int mi = 0; mi < 2; ++mi) {
        size_t m = m0 + w * 32 + mi * 16 + r16;
        const char* xrow = (const char*)Xr + m * 512;
        int swz = ((int)m & 7) << 4;
        #pragma unroll
        for (int ks = 0; ks < 8; ++ks)
            xf[mi][ks] = *(const bf16x8*)(xrow + ((ks * 64 + kq * 16) ^ swz));
    }

    f32x4 acc[2][8] = {};   // out accumulator: [mi][oi], o = oi*16 + kq*4 + j

    for (int t = 0; t < 8; ++t) {
        // ---- stage W1 tile: rows t*64..t*64+63 = contiguous 32 KB ----
        {
            const char* src = (const char*)W1T + (size_t)t * 32768;
            #pragma unroll
            for (int i = 0; i < 8; ++i) {
                int off = i * 4096 + tid * 16;
                gload16(src + off, W1l + off);
            }
        }
        // ---- stage W2 h-slice: [128 o][128 B sub-chunk at t*128] ----
        {
            #pragma unroll
            for (int i = 0; i < 4; ++i) {
                int p = tid + i * 256;
                int o = p >> 3, c16 = (p & 7) * 16;
                const char* src = (const char*)W2T + (size_t)o * 1024 + t * 128 + c16;
                gload16(src, W2l + o * 128 + c16);  // = W2l + p*16: lane-linear
            }
        }
        __syncthreads();    // drains vmcnt; staged tiles visible

        // ---- phase 1: S = X @ W1tile^T, bias+gelu -> bounce (bf16) ----
        #pragma unroll
        for (int ni = 0; ni < 4; ++ni) {
            f32x4 s0 = {}, s1 = {};
            #pragma unroll
            for (int ks = 0; ks < 8; ++ks) {
                bf16x8 a = *(const bf16x8*)(W1l + (ni * 16 + r16) * 512 +
                                            ((ks * 64 + kq * 16) ^ rmask));
                s0 = __builtin_amdgcn_mfma_f32_16x16x32_bf16(a, xf[0][ks], s0, 0, 0, 0);
                s1 = __builtin_amdgcn_mfma_f32_16x16x32_bf16(a, xf[1][ks], s1, 0, 0, 0);
            }
            float4 bv = *(const float4*)(b1f + t * 64 + ni * 16 + kq * 4);
            // mi=0 rows [0..15], mi=1 rows [16..31]; row&7 == r16&7 for both
            uint2 pk0, pk1;
            pk0.x = (unsigned int)f32_to_bf16(gelu_f(s0[0] + bv.x)) |
                    ((unsigned int)f32_to_bf16(gelu_f(s0[1] + bv.y)) << 16);
            pk0.y = (unsigned int)f32_to_bf16(gelu_f(s0[2] + bv.z)) |
                    ((unsigned int)f32_to_bf16(gelu_f(s0[3] + bv.w)) << 16);
            pk1.x = (unsigned int)f32_to_bf16(gelu_f(s1[0] + bv.x)) |
                    ((unsigned int)f32_to_bf16(gelu_f(s1[1] + bv.y)) << 16);
            pk1.y = (unsigned int)f32_to_bf16(gelu_f(s1[2] + bv.z)) |
                    ((unsigned int)f32_to_bf16(gelu_f(s1[3] + bv.w)) << 16);
            int colb = (ni * 32 + kq * 8) ^ rmask;
            *(uint2*)(bnc + r16 * 128 + colb) = pk0;
            *(uint2*)(bnc + (16 + r16) * 128 + colb) = pk1;
        }
        // wave-private bounce: same-wave write->read ordering via lgkmcnt
        // (compiler-inserted); no cross-wave sharing -> no barrier.

        // ---- phase 2: acc_out += gelu(S) @ W2slice^T (each read -> 2 mfma) --
        #pragma unroll
        for (int c = 0; c < 2; ++c) {
            int colb = (c * 64 + kq * 16) ^ rmask;
            bf16x8 b0 = *(const bf16x8*)(bnc + r16 * 128 + colb);
            bf16x8 b1 = *(const bf16x8*)(bnc + (16 + r16) * 128 + colb);
            #pragma unroll
            for (int oi = 0; oi < 8; ++oi) {
                bf16x8 a = *(const bf16x8*)(W2l + (oi * 16 + r16) * 128 + colb);
                acc[0][oi] = __builtin_amdgcn_mfma_f32_16x16x32_bf16(a, b0, acc[0][oi], 0, 0, 0);
                acc[1][oi] = __builtin_amdgcn_mfma_f32_16x16x32_bf16(a, b1, acc[1][oi], 0, 0, 0);
            }
        }
        __syncthreads();    // all LDS reads done before next tile overwrites
    }

    // ---- epilogue: bias2 + store (f32) ----
    #pragma unroll
    for (int mi = 0; mi < 2; ++mi) {
        size_t m = m0 + w * 32 + mi * 16 + r16;
        if (m >= N_NODES) continue;
        float* orow = outp + m * DIM;
        #pragma unroll
        for (int oi = 0; oi < 8; ++oi) {
            float4 bv = *(const float4*)(b2f + oi * 16 + kq * 4);
            float4 o;
            o.x = acc[mi][oi][0] + bv.x;
            o.y = acc[mi][oi][1] + bv.y;
            o.z = acc[mi][oi][2] + bv.z;
            o.w = acc[mi][oi][3] + bv.w;
            *(float4*)(orow + oi * 16 + kq * 4) = o;
        }
    }
}

// ---------------------------------------------------------------------------
extern "C" void kernel_launch(void* const* d_in, const int* in_sizes, int n_in,
                              void* d_out, int out_size, void* d_ws, size_t ws_size,
                              hipStream_t stream) {
    const float* h  = (const float*)d_in[0];
    const int*   ei = (const int*)d_in[1];
    const float* W1 = (const float*)d_in[2];
    const float* b1 = (const float*)d_in[3];
    const float* W2 = (const float*)d_in[4];
    const float* b2 = (const float*)d_in[5];
    float* out = (float*)d_out;

    // workspace layout (hdn eliminated)
    unsigned short* X   = (unsigned short*)d_ws;             // MROWS_PAD*256 bf16
    unsigned short* W1T = X + (size_t)MROWS_PAD * 256;       // 512*256 bf16
    unsigned short* W2T = W1T + 512 * 256;                   // 128*512 bf16
    int* cnt = (int*)(W2T + 128 * 512);                      // N
    int* row_start = cnt + N_NODES;                          // N+1
    int* bsum = row_start + N_NODES + 1;                     // 128
    int* csr = bsum + 128;                                   // E

    hipMemsetAsync(cnt, 0, N_NODES * sizeof(int), stream);
    mgl_prep_kernel<<<PREP_TOTAL, 256, 0, stream>>>(h, ei, W1, W2, X, W1T, W2T, cnt);
    mgl_scan_block_kernel<<<SCAN_NBLK, 256, 0, stream>>>(cnt, row_start, bsum);
    mgl_scan_bsum_kernel<<<1, 128, 0, stream>>>(bsum);
    mgl_scan_add_kernel<<<(N_NODES + 255) / 256, 256, 0, stream>>>(row_start, bsum);
    mgl_fill_kernel<<<(EDGES + 255) / 256, 256, 0, stream>>>(ei, row_start, cnt, csr);
    mgl_gather_mean_kernel<<<(N_NODES + 3) / 4, 256, 0, stream>>>(X, row_start, csr, X);

    // fused MLP v2: one block per 128 rows (782 blocks, 256 thr, 2/CU)
    mgl_fused_mlp_kernel<<<MROWS_PAD / 128, 256, 0, stream>>>(
        W1T, W2T, X, b1, b2, out);
}